// Round 25
// baseline (137.911 us; speedup 1.0000x reference)
//
#include <hip/hip_runtime.h>
#include <math.h>

#define IN_F 512
#define OUTF 128
#define NEG_SLOPE 0.2f

typedef __attribute__((ext_vector_type(8))) short bf16x8;
typedef __attribute__((ext_vector_type(4))) float f32x4;
typedef __attribute__((ext_vector_type(4))) unsigned u32x4;

// proj1 MFMA: 256 thr = 4 waves; W in 16 bf16x8 REGISTERS; A-fragments loaded
// DIRECTLY from global with pi-permuted k-order so each dwordx4 instruction
// covers contiguous 64B per row (pi(g,j): k = g*4+j (j<4), 16+g*4+j-4 (j>=4);
// B-fragments built with the same pi -> results identical). Zero LDS in proj.
#define P1T 256
#define NKS 16
#define PFD 4
#define BPSH 8192

// bucketing
#define NPB 128
#define NBMAX 784
#define EPB 8192
#define SRCMASK 0x1FFFF
#define CAP 2944

__device__ __forceinline__ unsigned pkbf(float a, float b) {  // RNE bf16 pack
  unsigned ua = __float_as_uint(a); ua += 0x7FFF + ((ua >> 16) & 1);
  unsigned ub = __float_as_uint(b); ub += 0x7FFF + ((ub >> 16) & 1);
  return (ua >> 16) | (ub & 0xFFFF0000u);
}

// ---------------- prep: fold weights -> pi-permuted bf16 B-fragments ----------------
__global__ void k_prep(const float* __restrict__ fc1, const float* __restrict__ al1,
                       const float* __restrict__ ar1, const float* __restrict__ fc2,
                       const float* __restrict__ al2, const float* __restrict__ ar2,
                       unsigned short* __restrict__ Bp,
                       float* __restrict__ w2al, float* __restrict__ w2ar,
                       int* __restrict__ bucketCursor) {
  __shared__ float wlds[IN_F * 12];
  int t = threadIdx.x;
  if (blockIdx.x == 0) {
    int k = t;  // 512 threads, one k-row each
#pragma unroll
    for (int h = 0; h < 4; ++h) {
      float wl = 0.f, wr = 0.f, wb = 0.f;
#pragma unroll
      for (int j = 0; j < 4; ++j) {
        float wv = fc1[k * 16 + h * 4 + j];
        wl = fmaf(wv, al1[h * 4 + j], wl);
        wr = fmaf(wv, ar1[h * 4 + j], wr);
        wb += wv;
      }
      wlds[k * 12 + h] = wl;          // cols 0-3: el
      wlds[k * 12 + 4 + h] = wr;      // cols 4-7: er
      wlds[k * 12 + 8 + h] = 0.25f * wb;  // cols 8-11: hbar
    }
    __syncthreads();
    // B fragments with pi: canonical elem e of lane l (g=l>>4) holds
    // k = kb + g*4 + e (e<4)  |  kb + 16 + g*4 + (e-4) (e>=4)
    for (int item = t; item < NKS * 64; item += 512) {
      int s = item >> 6, l = item & 63;
      int col = l & 15;
      int g = l >> 4;
      int kb = s * 32;
      unsigned hi[4];
#pragma unroll
      for (int p = 0; p < 4; ++p) {
        int e0 = 2 * p, e1 = 2 * p + 1;
        int k0 = kb + ((e0 < 4) ? (g * 4 + e0) : (16 + g * 4 + e0 - 4));
        int k1 = kb + ((e1 < 4) ? (g * 4 + e1) : (16 + g * 4 + e1 - 4));
        float w0 = (col < 12) ? wlds[k0 * 12 + col] : 0.f;
        float w1 = (col < 12) ? wlds[k1 * 12 + col] : 0.f;
        hi[p] = pkbf(w0, w1);
      }
      *(uint4*)&Bp[item * 8] = make_uint4(hi[0], hi[1], hi[2], hi[3]);
    }
  } else {
    if (t < 8) {
      int h = t >> 1;
      const float* a = (t & 1) ? ar2 : al2;
      float s = 0.f;
#pragma unroll 16
      for (int c = 0; c < OUTF; ++c) s += fc2[h * OUTF + c] * a[c];
      if (t & 1) w2ar[h] = s; else w2al[h] = s;
    }
    for (int i = t; i < NBMAX; i += 512) bucketCursor[i] = 0;
  }
}

// ---------------- fused A: [bscat (low blocks) | proj1 direct-load MFMA] ----------------
__global__ __launch_bounds__(P1T) void k_A(
    const float* __restrict__ x, const unsigned short* __restrict__ Bp,
    float* __restrict__ pk1, float* __restrict__ er1, int n,
    const int* __restrict__ src, const int* __restrict__ dst,
    int* __restrict__ bucketCursor, unsigned* __restrict__ ep, int e,
    int binBlocks, int projBlocks)
{
  __shared__ int hist[NBMAX];
  __shared__ int base[NBMAX];
  __shared__ int lcur[NBMAX];
  const int t = threadIdx.x;

  if ((int)blockIdx.x < binBlocks) {
    // ---------- bscat ----------
    const int bb = blockIdx.x;
    for (int i = t; i < NBMAX; i += P1T) hist[i] = 0;
    __syncthreads();
    int blockBase = bb * EPB;
#pragma unroll
    for (int i = 0; i < EPB / P1T; ++i) {
      int idx = blockBase + t + i * P1T;
      if (idx < e) atomicAdd(&hist[dst[idx] >> 7], 1);
    }
    __syncthreads();
    for (int i = t; i < NBMAX; i += P1T) {
      if (hist[i] > 0) base[i] = atomicAdd(&bucketCursor[i], hist[i]);
      lcur[i] = 0;
    }
    __syncthreads();
#pragma unroll
    for (int i = 0; i < EPB / P1T; ++i) {
      int idx = blockBase + t + i * P1T;
      if (idx < e) {
        int d = dst[idx];
        int b = d >> 7;
        int off = base[b] + atomicAdd(&lcur[b], 1);
        if (off < CAP)
          ep[(size_t)b * CAP + off] = (unsigned)src[idx] | ((unsigned)(d & (NPB - 1)) << 17);
      }
    }
  } else {
    // ---------- proj1: direct-load, pi-permuted, persistent register queue ----------
    const int pb = blockIdx.x - binBlocks;
    const int lane = t & 63;
    const int wv = t >> 6;
    const int R = lane & 15;                   // row within tile
    const int g = lane >> 4;                   // k-group

    bf16x8 Breg[NKS];
#pragma unroll
    for (int i = 0; i < NKS; ++i)
      Breg[i] = *(const bf16x8*)&Bp[(i * 64 + lane) * 8];

    const int totalWaves = projBlocks * 4;
    const long tileStride = (long)totalWaves * 16 * IN_F;   // floats per rt step
    const int rtMax = (n + 15) >> 4;           // 6250; N%16==0 -> all tiles full
    const int rt0 = pb * 4 + wv;
    if (rt0 < rtMax) {
      // per-thread base: row (rt*16 + R), k-offset g*4
      const float* xr = x + (size_t)(rt0 * 16 + R) * IN_F + g * 4;

      float4 q[PFD][2];
#pragma unroll
      for (int p = 0; p < PFD; ++p) {          // prime: ksteps 0..3 of tile rt0
        q[p][0] = *(const float4*)&xr[p * 32];
        q[p][1] = *(const float4*)&xr[p * 32 + 16];
      }

      for (int rt = rt0; rt < rtMax; rt += totalWaves) {
        const bool hasNext = (rt + totalWaves) < rtMax;
        const float* xrN = xr + tileStride;
        f32x4 acc = {0.f, 0.f, 0.f, 0.f};

#pragma unroll
        for (int ks = 0; ks < NKS; ++ks) {     // fully unrolled -> static q idx
          const int slot = ks & (PFD - 1);
          float4 a0 = q[slot][0], a1 = q[slot][1];
          if (ks + PFD < NKS) {                // refill from this tile
            q[slot][0] = *(const float4*)&xr[(ks + PFD) * 32];
            q[slot][1] = *(const float4*)&xr[(ks + PFD) * 32 + 16];
          } else if (hasNext) {                // wrap into next tile
            q[slot][0] = *(const float4*)&xrN[(ks + PFD - NKS) * 32];
            q[slot][1] = *(const float4*)&xrN[(ks + PFD - NKS) * 32 + 16];
          }
          u32x4 au = {pkbf(a0.x, a0.y), pkbf(a0.z, a0.w),
                      pkbf(a1.x, a1.y), pkbf(a1.z, a1.w)};
          union { u32x4 u; bf16x8 v; } cvt; cvt.u = au;
          acc = __builtin_amdgcn_mfma_f32_16x16x32_bf16(cvt.v, Breg[ks], acc, 0, 0, 0);
        }

        // D layout: col = lane&15, row = (lane>>4)*4 + i   [m89 verified]
        int col = lane & 15;
        int rbase = rt * 16 + (g * 4);
#pragma unroll
        for (int i = 0; i < 4; ++i) {
          int row = rbase + i;
          float v = acc[i];
          if (col < 4)       pk1[(size_t)row * 8 + col] = v;           // el
          else if (col < 8)  er1[(size_t)row * 4 + (col - 4)] = v;     // er
          else if (col < 12) pk1[(size_t)row * 8 + 4 + (col - 8)] = v; // hbar
        }
        xr = xrN;
      }
    }
  }
}

// ---------------- fused B: within-bucket sort + layer-1 aggregation ----------------
__global__ __launch_bounds__(256) void k_B(
    const unsigned* __restrict__ ep, const int* __restrict__ bucketCursor,
    unsigned* __restrict__ ep2, int* __restrict__ nodeBeg, int* __restrict__ nodeEnd,
    const float* __restrict__ pk1, const float* __restrict__ er1,
    const float* __restrict__ bias1,
    const float* __restrict__ w2al, const float* __restrict__ w2ar,
    float* __restrict__ pk2, float* __restrict__ er2, int n)
{
  __shared__ int cnt[NPB];
  __shared__ int scn[NPB];
  __shared__ int cur[NPB];
  __shared__ unsigned lbuf[CAP];
  int t = threadIdx.x;
  int b = blockIdx.x;
  int nodeBase = b * NPB;
  int m = bucketCursor[b];
  if (m > CAP) m = CAP;
  const unsigned* __restrict__ in = ep + (size_t)b * CAP;
  if (t < NPB) cnt[t] = 0;
  __syncthreads();
  for (int j = t; j < m; j += 256) atomicAdd(&cnt[in[j] >> 17], 1);
  __syncthreads();
  if (t < NPB) scn[t] = cnt[t];
  __syncthreads();
  for (int off = 1; off < NPB; off <<= 1) {
    int v = (t < NPB && t >= off) ? scn[t - off] : 0;
    __syncthreads();
    if (t < NPB) scn[t] += v;
    __syncthreads();
  }
  if (t < NPB) {
    int excl = scn[t] - cnt[t];
    int node = nodeBase + t;
    if (node < n) {
      nodeBeg[node] = b * CAP + excl;
      nodeEnd[node] = b * CAP + excl + cnt[t];
    }
    cur[t] = excl;
  }
  __syncthreads();
  for (int j = t; j < m; j += 256) {
    unsigned p = in[j];
    int pos = atomicAdd(&cur[p >> 17], 1);
    lbuf[pos] = p & SRCMASK;
  }
  __syncthreads();
  for (int i = t; i < m; i += 256) ep2[(size_t)b * CAP + i] = lbuf[i];  // for bagg2

#pragma unroll
  for (int half = 0; half < 2; ++half) {
    int w = t + half * 256;
    int i = w >> 2, h = w & 3;
    int node = nodeBase + i;
    bool active = node < n;
    float v = 0.f;
    if (active) {
      int beg = scn[i] - cnt[i], end = scn[i];
      float ern = er1[(size_t)node * 4 + h];
      float den = 0.f, num = 0.f;
      for (int j = beg; j < end; ++j) {
        int s = (int)lbuf[j];
        float el = pk1[(size_t)s * 8 + h];
        float hb = pk1[(size_t)s * 8 + 4 + h];
        float eh = el + ern;
        eh = (eh > 0.f) ? eh : NEG_SLOPE * eh;
        float wg = __expf(eh);
        den += wg;
        num = fmaf(wg, hb, num);
      }
      float mb = 0.25f * (bias1[h*4] + bias1[h*4+1] + bias1[h*4+2] + bias1[h*4+3]);
      v = (end > beg) ? num / den : 0.f;
      v += mb;
      v = (v > 0.f) ? v : 0.f;
    }
    float pl = v * w2al[h];
    float pr = v * w2ar[h];
    pl += __shfl_xor(pl, 1); pl += __shfl_xor(pl, 2);
    pr += __shfl_xor(pr, 1); pr += __shfl_xor(pr, 2);
    if (active) {
      pk2[(size_t)node * 8 + h] = v;
      if (h == 0) { pk2[(size_t)node * 8 + 4] = pl; er2[node] = pr; }
    }
  }
}

// ---------------- layer 2 aggregation: thread-per-node + block output epilogue ----------------
__global__ __launch_bounds__(256) void k_bagg2(
    const unsigned* __restrict__ ep2, const int* __restrict__ nodeBeg,
    const int* __restrict__ nodeEnd,
    const float* __restrict__ pk2, const float* __restrict__ er2,
    const float* __restrict__ w2, const float* __restrict__ bias2,
    float* __restrict__ out, int n)
{
  __shared__ float gacc[256 * 4];
  __shared__ float w2s[4 * OUTF];
  __shared__ float b2s[OUTF];
  int t = threadIdx.x;
  int nodeBase = blockIdx.x * 256;
  int nn = nodeBase + t;
  for (int i = t; i < 4 * OUTF; i += 256) w2s[i] = w2[i];
  if (t < OUTF) b2s[t] = bias2[t];
  float g0 = 0.f, g1 = 0.f, g2 = 0.f, g3 = 0.f;
  if (nn < n) {
    int beg = nodeBeg[nn], end = nodeEnd[nn];
    float ern = er2[nn];
    float den = 0.f;
    for (int j = beg; j < end; ++j) {
      int s = (int)ep2[j];
      const float* __restrict__ ps = &pk2[(size_t)s * 8];
      float4 hv = *(const float4*)ps;
      float e = ps[4] + ern;
      e = (e > 0.f) ? e : NEG_SLOPE * e;
      float w = __expf(e);
      den += w;
      g0 = fmaf(w, hv.x, g0); g1 = fmaf(w, hv.y, g1);
      g2 = fmaf(w, hv.z, g2); g3 = fmaf(w, hv.w, g3);
    }
    float inv = (end > beg) ? 1.0f / den : 0.f;
    g0 *= inv; g1 *= inv; g2 *= inv; g3 *= inv;
  }
  gacc[t * 4 + 0] = g0; gacc[t * 4 + 1] = g1;
  gacc[t * 4 + 2] = g2; gacc[t * 4 + 3] = g3;
  __syncthreads();
  for (int idx = t; idx < 256 * (OUTF / 2); idx += 256) {
    int i = idx >> 6;
    int node = nodeBase + i;
    if (node >= n) continue;
    int c = (idx & 63) * 2;
    float gx = gacc[i*4], gy = gacc[i*4+1], gz = gacc[i*4+2], gw = gacc[i*4+3];
    float2 o;
    o.x = gx*w2s[c]   + gy*w2s[OUTF+c]   + gz*w2s[2*OUTF+c]   + gw*w2s[3*OUTF+c]   + b2s[c];
    o.y = gx*w2s[c+1] + gy*w2s[OUTF+c+1] + gz*w2s[2*OUTF+c+1] + gw*w2s[3*OUTF+c+1] + b2s[c+1];
    *(float2*)&out[(size_t)node * OUTF + c] = o;
  }
}

// ---------------- launch ----------------
extern "C" void kernel_launch(void* const* d_in, const int* in_sizes, int n_in,
                              void* d_out, int out_size, void* d_ws, size_t ws_size,
                              hipStream_t stream) {
  const float* nfeats = (const float*)d_in[0];
  const int*   srcp   = (const int*)d_in[2];
  const int*   dstp   = (const int*)d_in[3];
  const float* fc1    = (const float*)d_in[4];
  const float* al1    = (const float*)d_in[5];
  const float* ar1    = (const float*)d_in[6];
  const float* bias1  = (const float*)d_in[7];
  const float* fc2    = (const float*)d_in[8];
  const float* al2    = (const float*)d_in[9];
  const float* ar2    = (const float*)d_in[10];
  const float* bias2  = (const float*)d_in[11];

  const int N = in_sizes[0] / IN_F;     // 100000
  const int E = in_sizes[2];            // 1600000
  const int NB = (N + NPB - 1) / NPB;   // 782

  float* ws   = (float*)d_ws;
  float* pk1  = ws;                          // 8N  {el[4], hb[4]}
  float* er1  = pk1 + (size_t)8 * N;         // 4N
  float* pk2  = er1 + (size_t)4 * N;         // 8N  {h2in[4], el2, pad[3]}
  float* er2  = pk2 + (size_t)8 * N;         // N
  float* w2al = er2 + N;                     // 4
  float* w2ar = w2al + 4;                    // 4
  unsigned short* Bp = (unsigned short*)(w2ar + 4);     // 8192
  int* bucketCursor = (int*)(Bp + BPSH);     // NBMAX
  int* nodeBeg      = bucketCursor + NBMAX;  // N
  int* nodeEnd      = nodeBeg + N;           // N
  unsigned* ep      = (unsigned*)(nodeEnd + N);       // NB*CAP
  unsigned* ep2     = ep + (size_t)NB * CAP;          // NB*CAP

  const int binBlocks = (E + EPB - 1) / EPB;     // 196
  const int projBlocks = 828;                    // 196+828 = 1024 = 4 blocks/CU

  k_prep<<<2, 512, 0, stream>>>(fc1, al1, ar1, fc2, al2, ar2,
                                Bp, w2al, w2ar, bucketCursor);
  k_A<<<binBlocks + projBlocks, P1T, 0, stream>>>(nfeats, Bp, pk1, er1, N,
                                                  srcp, dstp, bucketCursor, ep, E,
                                                  binBlocks, projBlocks);
  k_B<<<NB, 256, 0, stream>>>(ep, bucketCursor, ep2, nodeBeg, nodeEnd,
                              pk1, er1, bias1, w2al, w2ar, pk2, er2, N);
  k_bagg2<<<(N + 255) / 256, 256, 0, stream>>>(ep2, nodeBeg, nodeEnd, pk2, er2,
                                               fc2, bias2, (float*)d_out, N);
}

// Round 26
// 132.883 us; speedup vs baseline: 1.0378x; 1.0378x over previous
//
#include <hip/hip_runtime.h>
#include <math.h>

#define IN_F 512
#define OUTF 128
#define NEG_SLOPE 0.2f

typedef __attribute__((ext_vector_type(8))) short bf16x8;
typedef __attribute__((ext_vector_type(4))) float f32x4;
typedef __attribute__((ext_vector_type(4))) unsigned u32x4;
typedef const __attribute__((address_space(1))) void gvoid;
typedef __attribute__((address_space(3))) void lvoid;

// proj1 MFMA: 256 thr = 4 waves; W in 16 bf16x8 REGISTERS; x staged f32 via
// global_load_lds into a per-wave 3-deep ring of 16x64 tiles (4KB each).
// Counted vmcnt(8): 3 tiles (12 loads) in flight per wave continuously.
#define P1T 256
#define NKS 16
#define BPSH 8192
#define TW 64                 // tile width (f32 cols)
#define TILE_B (16 * TW * 4)  // 4096 B per ring buffer
#define RING 3

// bucketing
#define NPB 128
#define NBMAX 784
#define EPB 8192
#define SRCMASK 0x1FFFF
#define CAP 2944

#define SMEM_A (4 * RING * TILE_B)       // 49152 -> 3 blocks/CU

__device__ __forceinline__ unsigned pkbf(float a, float b) {  // RNE bf16 pack
  unsigned ua = __float_as_uint(a); ua += 0x7FFF + ((ua >> 16) & 1);
  unsigned ub = __float_as_uint(b); ub += 0x7FFF + ((ub >> 16) & 1);
  return (ua >> 16) | (ub & 0xFFFF0000u);
}

#define VMCNT8() do { asm volatile("s_waitcnt vmcnt(8)" ::: "memory"); \
                      __builtin_amdgcn_sched_barrier(0); } while (0)
#define VMCNT4() do { asm volatile("s_waitcnt vmcnt(4)" ::: "memory"); \
                      __builtin_amdgcn_sched_barrier(0); } while (0)
#define VMCNT0() do { asm volatile("s_waitcnt vmcnt(0)" ::: "memory"); \
                      __builtin_amdgcn_sched_barrier(0); } while (0)

// issue one 16x64 f32 tile (4 gload_lds x 1KB); LDS linear, source pre-swizzled:
// LDS(r, c16) <- global(r, c16 ^ (r&7))   [16B units; read side applies same XOR]
__device__ __forceinline__ void issue_tile(const float* __restrict__ x, int wrow,
                                           int kbase, char* lbase, int lane) {
#pragma unroll
  for (int i = 0; i < 4; ++i) {
    int f = lane + i * 64;
    int r = f >> 4, c16 = f & 15;
    int srcu = c16 ^ (r & 7);
    const float* g = x + (size_t)(wrow + r) * IN_F + kbase + srcu * 4;
    __builtin_amdgcn_global_load_lds((gvoid*)g, (lvoid*)(lbase + i * 1024), 16, 0, 0);
  }
}

// ---------------- prep: fold weights -> bf16 MFMA B-fragments ----------------
__global__ void k_prep(const float* __restrict__ fc1, const float* __restrict__ al1,
                       const float* __restrict__ ar1, const float* __restrict__ fc2,
                       const float* __restrict__ al2, const float* __restrict__ ar2,
                       unsigned short* __restrict__ Bp,
                       float* __restrict__ w2al, float* __restrict__ w2ar,
                       int* __restrict__ bucketCursor) {
  __shared__ float wlds[IN_F * 12];
  int t = threadIdx.x;
  if (blockIdx.x == 0) {
    int k = t;  // 512 threads, one k-row each
#pragma unroll
    for (int h = 0; h < 4; ++h) {
      float wl = 0.f, wr = 0.f, wb = 0.f;
#pragma unroll
      for (int j = 0; j < 4; ++j) {
        float wv = fc1[k * 16 + h * 4 + j];
        wl = fmaf(wv, al1[h * 4 + j], wl);
        wr = fmaf(wv, ar1[h * 4 + j], wr);
        wb += wv;
      }
      wlds[k * 12 + h] = wl;
      wlds[k * 12 + 4 + h] = wr;
      wlds[k * 12 + 8 + h] = 0.25f * wb;
    }
    __syncthreads();
    for (int item = t; item < NKS * 64; item += 512) {
      int s = item >> 6, l = item & 63;
      int col = l & 15;
      int kb = s * 32 + ((l >> 4) * 8);
      unsigned hi[4];
#pragma unroll
      for (int p = 0; p < 4; ++p) {
        float w0 = 0.f, w1 = 0.f;
        if (col < 12) {
          w0 = wlds[(kb + 2 * p) * 12 + col];
          w1 = wlds[(kb + 2 * p + 1) * 12 + col];
        }
        hi[p] = pkbf(w0, w1);
      }
      *(uint4*)&Bp[item * 8] = make_uint4(hi[0], hi[1], hi[2], hi[3]);
    }
  } else {
    if (t < 8) {
      int h = t >> 1;
      const float* a = (t & 1) ? ar2 : al2;
      float s = 0.f;
#pragma unroll 16
      for (int c = 0; c < OUTF; ++c) s += fc2[h * OUTF + c] * a[c];
      if (t & 1) w2ar[h] = s; else w2al[h] = s;
    }
    for (int i = t; i < NBMAX; i += 512) bucketCursor[i] = 0;
  }
}

// ---------------- fused A: [bscat (low blocks) | proj1-MFMA gload_lds] ----------------
__global__ __launch_bounds__(P1T) void k_A(
    const float* __restrict__ x, const unsigned short* __restrict__ Bp,
    float* __restrict__ pk1, float* __restrict__ er1, int n,
    const int* __restrict__ src, const int* __restrict__ dst,
    int* __restrict__ bucketCursor, unsigned* __restrict__ ep, int e,
    int binBlocks, int projBlocks)
{
  __shared__ __align__(16) char smem[SMEM_A];
  const int t = threadIdx.x;

  if ((int)blockIdx.x < binBlocks) {
    // ---------- bscat ----------
    int* hist = (int*)smem;
    int* base = hist + NBMAX;
    int* lcur = base + NBMAX;
    const int bb = blockIdx.x;
    for (int i = t; i < NBMAX; i += P1T) hist[i] = 0;
    __syncthreads();
    int blockBase = bb * EPB;
#pragma unroll
    for (int i = 0; i < EPB / P1T; ++i) {
      int idx = blockBase + t + i * P1T;
      if (idx < e) atomicAdd(&hist[dst[idx] >> 7], 1);
    }
    __syncthreads();
    for (int i = t; i < NBMAX; i += P1T) {
      if (hist[i] > 0) base[i] = atomicAdd(&bucketCursor[i], hist[i]);
      lcur[i] = 0;
    }
    __syncthreads();
#pragma unroll
    for (int i = 0; i < EPB / P1T; ++i) {
      int idx = blockBase + t + i * P1T;
      if (idx < e) {
        int d = dst[idx];
        int b = d >> 7;
        int off = base[b] + atomicAdd(&lcur[b], 1);
        if (off < CAP)
          ep[(size_t)b * CAP + off] = (unsigned)src[idx] | ((unsigned)(d & (NPB - 1)) << 17);
      }
    }
  } else {
    // ---------- proj1 ----------
    const int pb = blockIdx.x - binBlocks;
    const int lane = t & 63;
    const int wv = t >> 6;
    char* ring = smem + (size_t)wv * (RING * TILE_B);   // wave-private ring

    bf16x8 Breg[NKS];
#pragma unroll
    for (int i = 0; i < NKS; ++i)
      Breg[i] = *(const bf16x8*)&Bp[(i * 64 + lane) * 8];

    const int R = lane & 15;
    const int g = lane >> 4;
    const int sw = R & 7;
    const int totalWaves = projBlocks * 4;
    const int rtMax = (n + 15) >> 4;       // 6250 (N divisible by 16: no tail)

    for (int rt = pb * 4 + wv; rt < rtMax; rt += totalWaves) {
      const int wrow = rt * 16;
      f32x4 acc = {0.f, 0.f, 0.f, 0.f};

      issue_tile(x, wrow, 0, ring + 0 * TILE_B, lane);
      issue_tile(x, wrow, TW, ring + 1 * TILE_B, lane);

#pragma unroll
      for (int T = 0; T < 8; ++T) {
        if (T < 6) issue_tile(x, wrow, (T + 2) * TW, ring + ((T + 2) % 3) * TILE_B, lane);
        if (T < 6)      { VMCNT8(); }
        else if (T == 6){ VMCNT4(); }
        else            { VMCNT0(); }
        const char* lb = ring + (T % 3) * TILE_B;
#pragma unroll
        for (int ks = 0; ks < 2; ++ks) {
          int j16 = ks * 8 + g * 2;
          float4 a0 = *(const float4*)(lb + R * 256 + ((j16) ^ sw) * 16);
          float4 a1 = *(const float4*)(lb + R * 256 + ((j16 + 1) ^ sw) * 16);
          u32x4 au = {pkbf(a0.x, a0.y), pkbf(a0.z, a0.w),
                      pkbf(a1.x, a1.y), pkbf(a1.z, a1.w)};
          union { u32x4 u; bf16x8 v; } cvt; cvt.u = au;
          acc = __builtin_amdgcn_mfma_f32_16x16x32_bf16(cvt.v, Breg[T * 2 + ks],
                                                        acc, 0, 0, 0);
        }
      }

      // D layout: col = lane&15, row = (lane>>4)*4 + i   [m89 verified]
      int col = lane & 15;
      int rbase = wrow + (g * 4);
#pragma unroll
      for (int i = 0; i < 4; ++i) {
        int row = rbase + i;
        if (row < n) {
          float v = acc[i];
          if (col < 4)       pk1[(size_t)row * 8 + col] = v;           // el
          else if (col < 8)  er1[(size_t)row * 4 + (col - 4)] = v;     // er
          else if (col < 12) pk1[(size_t)row * 8 + 4 + (col - 8)] = v; // hbar
        }
      }
    }
  }
}

// ---------------- fused B: within-bucket sort + layer-1 aggregation ----------------
__global__ __launch_bounds__(256) void k_B(
    const unsigned* __restrict__ ep, const int* __restrict__ bucketCursor,
    unsigned* __restrict__ ep2, int* __restrict__ nodeBeg, int* __restrict__ nodeEnd,
    const float* __restrict__ pk1, const float* __restrict__ er1,
    const float* __restrict__ bias1,
    const float* __restrict__ w2al, const float* __restrict__ w2ar,
    float* __restrict__ pk2, float* __restrict__ er2, int n)
{
  __shared__ int cnt[NPB];
  __shared__ int scn[NPB];
  __shared__ int cur[NPB];
  __shared__ unsigned lbuf[CAP];
  int t = threadIdx.x;
  int b = blockIdx.x;
  int nodeBase = b * NPB;
  int m = bucketCursor[b];
  if (m > CAP) m = CAP;
  const unsigned* __restrict__ in = ep + (size_t)b * CAP;
  if (t < NPB) cnt[t] = 0;
  __syncthreads();
  for (int j = t; j < m; j += 256) atomicAdd(&cnt[in[j] >> 17], 1);
  __syncthreads();
  if (t < NPB) scn[t] = cnt[t];
  __syncthreads();
  for (int off = 1; off < NPB; off <<= 1) {
    int v = (t < NPB && t >= off) ? scn[t - off] : 0;
    __syncthreads();
    if (t < NPB) scn[t] += v;
    __syncthreads();
  }
  if (t < NPB) {
    int excl = scn[t] - cnt[t];
    int node = nodeBase + t;
    if (node < n) {
      nodeBeg[node] = b * CAP + excl;
      nodeEnd[node] = b * CAP + excl + cnt[t];
    }
    cur[t] = excl;
  }
  __syncthreads();
  for (int j = t; j < m; j += 256) {
    unsigned p = in[j];
    int pos = atomicAdd(&cur[p >> 17], 1);
    lbuf[pos] = p & SRCMASK;
  }
  __syncthreads();
  for (int i = t; i < m; i += 256) ep2[(size_t)b * CAP + i] = lbuf[i];  // for bagg2

#pragma unroll
  for (int half = 0; half < 2; ++half) {
    int w = t + half * 256;
    int i = w >> 2, h = w & 3;
    int node = nodeBase + i;
    bool active = node < n;
    float v = 0.f;
    if (active) {
      int beg = scn[i] - cnt[i], end = scn[i];
      float ern = er1[(size_t)node * 4 + h];
      float den = 0.f, num = 0.f;
      for (int j = beg; j < end; ++j) {
        int s = (int)lbuf[j];
        float el = pk1[(size_t)s * 8 + h];
        float hb = pk1[(size_t)s * 8 + 4 + h];
        float eh = el + ern;
        eh = (eh > 0.f) ? eh : NEG_SLOPE * eh;
        float wg = __expf(eh);
        den += wg;
        num = fmaf(wg, hb, num);
      }
      float mb = 0.25f * (bias1[h*4] + bias1[h*4+1] + bias1[h*4+2] + bias1[h*4+3]);
      v = (end > beg) ? num / den : 0.f;
      v += mb;
      v = (v > 0.f) ? v : 0.f;
    }
    float pl = v * w2al[h];
    float pr = v * w2ar[h];
    pl += __shfl_xor(pl, 1); pl += __shfl_xor(pl, 2);
    pr += __shfl_xor(pr, 1); pr += __shfl_xor(pr, 2);
    if (active) {
      pk2[(size_t)node * 8 + h] = v;
      if (h == 0) { pk2[(size_t)node * 8 + 4] = pl; er2[node] = pr; }
    }
  }
}

// ---------------- layer 2 aggregation: thread-per-node + block output epilogue ----------------
__global__ __launch_bounds__(256) void k_bagg2(
    const unsigned* __restrict__ ep2, const int* __restrict__ nodeBeg,
    const int* __restrict__ nodeEnd,
    const float* __restrict__ pk2, const float* __restrict__ er2,
    const float* __restrict__ w2, const float* __restrict__ bias2,
    float* __restrict__ out, int n)
{
  __shared__ float gacc[256 * 4];
  __shared__ float w2s[4 * OUTF];
  __shared__ float b2s[OUTF];
  int t = threadIdx.x;
  int nodeBase = blockIdx.x * 256;
  int nn = nodeBase + t;
  for (int i = t; i < 4 * OUTF; i += 256) w2s[i] = w2[i];
  if (t < OUTF) b2s[t] = bias2[t];
  float g0 = 0.f, g1 = 0.f, g2 = 0.f, g3 = 0.f;
  if (nn < n) {
    int beg = nodeBeg[nn], end = nodeEnd[nn];
    float ern = er2[nn];
    float den = 0.f;
    for (int j = beg; j < end; ++j) {
      int s = (int)ep2[j];
      const float* __restrict__ ps = &pk2[(size_t)s * 8];
      float4 hv = *(const float4*)ps;
      float e = ps[4] + ern;
      e = (e > 0.f) ? e : NEG_SLOPE * e;
      float w = __expf(e);
      den += w;
      g0 = fmaf(w, hv.x, g0); g1 = fmaf(w, hv.y, g1);
      g2 = fmaf(w, hv.z, g2); g3 = fmaf(w, hv.w, g3);
    }
    float inv = (end > beg) ? 1.0f / den : 0.f;
    g0 *= inv; g1 *= inv; g2 *= inv; g3 *= inv;
  }
  gacc[t * 4 + 0] = g0; gacc[t * 4 + 1] = g1;
  gacc[t * 4 + 2] = g2; gacc[t * 4 + 3] = g3;
  __syncthreads();
  for (int idx = t; idx < 256 * (OUTF / 2); idx += 256) {
    int i = idx >> 6;
    int node = nodeBase + i;
    if (node >= n) continue;
    int c = (idx & 63) * 2;
    float gx = gacc[i*4], gy = gacc[i*4+1], gz = gacc[i*4+2], gw = gacc[i*4+3];
    float2 o;
    o.x = gx*w2s[c]   + gy*w2s[OUTF+c]   + gz*w2s[2*OUTF+c]   + gw*w2s[3*OUTF+c]   + b2s[c];
    o.y = gx*w2s[c+1] + gy*w2s[OUTF+c+1] + gz*w2s[2*OUTF+c+1] + gw*w2s[3*OUTF+c+1] + b2s[c+1];
    *(float2*)&out[(size_t)node * OUTF + c] = o;
  }
}

// ---------------- launch ----------------
extern "C" void kernel_launch(void* const* d_in, const int* in_sizes, int n_in,
                              void* d_out, int out_size, void* d_ws, size_t ws_size,
                              hipStream_t stream) {
  const float* nfeats = (const float*)d_in[0];
  const int*   srcp   = (const int*)d_in[2];
  const int*   dstp   = (const int*)d_in[3];
  const float* fc1    = (const float*)d_in[4];
  const float* al1    = (const float*)d_in[5];
  const float* ar1    = (const float*)d_in[6];
  const float* bias1  = (const float*)d_in[7];
  const float* fc2    = (const float*)d_in[8];
  const float* al2    = (const float*)d_in[9];
  const float* ar2    = (const float*)d_in[10];
  const float* bias2  = (const float*)d_in[11];

  const int N = in_sizes[0] / IN_F;     // 100000
  const int E = in_sizes[2];            // 1600000
  const int NB = (N + NPB - 1) / NPB;   // 782

  float* ws   = (float*)d_ws;
  float* pk1  = ws;                          // 8N  {el[4], hb[4]}
  float* er1  = pk1 + (size_t)8 * N;         // 4N
  float* pk2  = er1 + (size_t)4 * N;         // 8N  {h2in[4], el2, pad[3]}
  float* er2  = pk2 + (size_t)8 * N;         // N
  float* w2al = er2 + N;                     // 4
  float* w2ar = w2al + 4;                    // 4
  unsigned short* Bp = (unsigned short*)(w2ar + 4);     // 8192
  int* bucketCursor = (int*)(Bp + BPSH);     // NBMAX
  int* nodeBeg      = bucketCursor + NBMAX;  // N
  int* nodeEnd      = nodeBeg + N;           // N
  unsigned* ep      = (unsigned*)(nodeEnd + N);       // NB*CAP
  unsigned* ep2     = ep + (size_t)NB * CAP;          // NB*CAP

  const int binBlocks = (E + EPB - 1) / EPB;     // 196
  const int projBlocks = 572;                    // 196+572 = 768 = 3 blocks/CU

  k_prep<<<2, 512, 0, stream>>>(fc1, al1, ar1, fc2, al2, ar2,
                                Bp, w2al, w2ar, bucketCursor);
  k_A<<<binBlocks + projBlocks, P1T, 0, stream>>>(nfeats, Bp, pk1, er1, N,
                                                  srcp, dstp, bucketCursor, ep, E,
                                                  binBlocks, projBlocks);
  k_B<<<NB, 256, 0, stream>>>(ep, bucketCursor, ep2, nodeBeg, nodeEnd,
                              pk1, er1, bias1, w2al, w2ar, pk2, er2, N);
  k_bagg2<<<(N + 255) / 256, 256, 0, stream>>>(ep2, nodeBeg, nodeEnd, pk2, er2,
                                               fc2, bias2, (float*)d_out, N);
}